// Round 9
// baseline (643.735 us; speedup 1.0000x reference)
//
#include <hip/hip_runtime.h>

constexpr int N = 50000;
constexpr int E = 400000;
constexpr int D = 100;
constexpr int B = 4;
constexpr float NEG_SLOPE = 0.2f;

constexpr int SCAN_CHUNK = 2048;
constexpr int NB_SCAN = (N + SCAN_CHUNK - 1) / SCAN_CHUNK;  // 25
constexpr int CAP = 128;  // per-node LDS edge cache; deg>CAP falls back (Poisson(8): never)

// ---------------- CSR build (counting sort of edges by dst) ----------------

__global__ void k_hist(const int* __restrict__ dst, int* __restrict__ deg) {
  int i = blockIdx.x * blockDim.x + threadIdx.x;
  int stride = gridDim.x * blockDim.x;
  for (; i < E; i += stride) atomicAdd(&deg[dst[i]], 1);
}

__global__ void k_scan1(const int* __restrict__ deg, int* __restrict__ incl,
                        int* __restrict__ bsums) {
  __shared__ int lds[256];
  int tid = threadIdx.x;
  int base = blockIdx.x * SCAN_CHUNK + tid * 8;
  int v[8]; int s = 0;
#pragma unroll
  for (int j = 0; j < 8; ++j) {
    int idx = base + j;
    int x = (idx < N) ? deg[idx] : 0;
    v[j] = x; s += x;
  }
  lds[tid] = s; __syncthreads();
  for (int off = 1; off < 256; off <<= 1) {
    int t = (tid >= off) ? lds[tid - off] : 0;
    __syncthreads();
    lds[tid] += t;
    __syncthreads();
  }
  int run = lds[tid] - s;  // exclusive prefix within block
#pragma unroll
  for (int j = 0; j < 8; ++j) {
    int idx = base + j;
    run += v[j];
    if (idx < N) incl[idx] = run;  // inclusive scan within block
  }
  if (tid == 255) bsums[blockIdx.x] = lds[255];
}

__global__ void k_scan2(int* __restrict__ bsums, int nb) {
  if (threadIdx.x == 0 && blockIdx.x == 0) {
    int run = 0;
    for (int i = 0; i < nb; ++i) { int t = bsums[i]; bsums[i] = run; run += t; }
  }
}

__global__ void k_scan3(const int* __restrict__ incl, const int* __restrict__ bsums,
                        int* __restrict__ offs) {
  int i = blockIdx.x * blockDim.x + threadIdx.x;
  int stride = gridDim.x * blockDim.x;
  for (; i < N; i += stride) {
    offs[i + 1] = incl[i] + bsums[i / SCAN_CHUNK];
    if (i == 0) offs[0] = 0;
  }
}

// scatter edges into CSR order; permute src/etype into position order so
// downstream kernels read contiguous ranges (no indirect per-edge gathers).
__global__ void k_scatter(const int* __restrict__ srcArr, const int* __restrict__ dst,
                          const int* __restrict__ etype, const int* __restrict__ offs,
                          int* __restrict__ cursor, int* __restrict__ ssorted,
                          int* __restrict__ esorted) {
  int i = blockIdx.x * blockDim.x + threadIdx.x;
  int stride = gridDim.x * blockDim.x;
  for (; i < E; i += stride) {
    int d = dst[i];
    int pos = offs[d] + atomicAdd(&cursor[d], 1);
    ssorted[pos] = srcArr[i];
    esorted[pos] = etype[i];
  }
}

// X1[n,:] = emb[entity[n],:]  — hoist the remap so edge gathers are 1-hop.
__global__ void k_gather(const float* __restrict__ emb, const int* __restrict__ entity,
                         float* __restrict__ X) {
  int idx = blockIdx.x * blockDim.x + threadIdx.x;  // float4 index
  int total = N * (D / 4);
  int stride = gridDim.x * blockDim.x;
  for (; idx < total; idx += stride) {
    int n = idx / (D / 4), c = idx % (D / 4);
    int r = entity[n];
    *(float4*)(X + (size_t)n * D + c * 4) = *(const float4*)(emb + (size_t)r * D + c * 4);
  }
}

// ---------------- per-layer kernels ----------------

// qb[b,i] = sum_o basis[b,i,o] * q[o];  kb likewise.
__global__ void k_qbkb(const float* __restrict__ basis, const float* __restrict__ qv,
                       const float* __restrict__ kv, float* __restrict__ qb,
                       float* __restrict__ kb) {
  int t = blockIdx.x * blockDim.x + threadIdx.x;
  if (t < B * D) {
    const float* row = basis + t * D;  // t = b*D+i -> row (b,i,:)
    float sq = 0.f, sk = 0.f;
    for (int o = 0; o < D; ++o) { float r = row[o]; sq += r * qv[o]; sk += r * kv[o]; }
    qb[t] = sq; kb[t] = sk;
  }
}

// xq[n,b] = x[n,:].qb[b,:] ; xk[n,b] = x[n,:].kb[b,:]   — thread per node.
__global__ __launch_bounds__(256) void k_xqxk(
    const float* __restrict__ X, const float* __restrict__ qb,
    const float* __restrict__ kb, float* __restrict__ xq, float* __restrict__ xk) {
  __shared__ float qb_s[B * D], kb_s[B * D];
  int tid = threadIdx.x;
  for (int i = tid; i < B * D; i += 256) { qb_s[i] = qb[i]; kb_s[i] = kb[i]; }
  __syncthreads();
  int n = blockIdx.x * 256 + tid;
  if (n >= N) return;
  const float* x = X + (size_t)n * D;
  float aq[B] = {}, ak[B] = {};
  for (int i = 0; i < D; i += 4) {
    float4 xv = *(const float4*)(x + i);
#pragma unroll
    for (int b = 0; b < B; ++b) {
      float4 qv = *(const float4*)&qb_s[b * D + i];
      float4 kv = *(const float4*)&kb_s[b * D + i];
      aq[b] += xv.x * qv.x + xv.y * qv.y + xv.z * qv.z + xv.w * qv.w;
      ak[b] += xv.x * kv.x + xv.y * kv.y + xv.z * kv.z + xv.w * kv.w;
    }
  }
  *(float4*)(xq + (size_t)n * 4) = make_float4(aq[0], aq[1], aq[2], aq[3]);
  *(float4*)(xk + (size_t)n * 4) = make_float4(ak[0], ak[1], ak[2], ak[3]);
}

__device__ __forceinline__ float edge_score_p(int s, int et,
                                              const float* __restrict__ att,
                                              const float4 xq4,
                                              const float* __restrict__ xk,
                                              float4* a_out) {
  float4 a = *(const float4*)(att + et * 4);
  float4 xs = *(const float4*)(xk + s * 4);
  float qe = a.x * xq4.x + a.y * xq4.y + a.z * xq4.z + a.w * xq4.w;
  float ke = a.x * xs.x + a.y * xs.y + a.z * xs.z + a.w * xs.w;
  float sc = qe + ke;
  *a_out = a;
  return sc >= 0.f ? sc : NEG_SLOPE * sc;
}

// One block (128 thr) per dst node: softmax over its edges + input-space aggregation.
// agg[n,b,:] = sum_edges alpha_e * att[et,b] * x[src,:]
__global__ __launch_bounds__(128) void k_node(
    const float* __restrict__ feat, const int* __restrict__ ssorted,
    const int* __restrict__ esorted, const float* __restrict__ att,
    const float* __restrict__ xq, const float* __restrict__ xk,
    const int* __restrict__ offs, float* __restrict__ agg) {
  int n = blockIdx.x;
  int tid = threadIdx.x;
  int lane = tid & 63, wid = tid >> 6;
  int o0 = offs[n], o1 = offs[n + 1];
  int deg = o1 - o0;
  float4 xq4 = *(const float4*)(xq + (size_t)n * 4);
  __shared__ float red[2];
  __shared__ float sc[CAP];
  __shared__ float4 a4[CAP];
  __shared__ int sbuf[CAP];

  if (deg <= CAP) {
    // compute each edge score ONCE; cache score, att-row, src in LDS
    for (int i = tid; i < deg; i += 128) {
      int s = ssorted[o0 + i];
      int et = esorted[o0 + i];
      float4 a;
      float v = edge_score_p(s, et, att, xq4, xk, &a);
      sc[i] = v; a4[i] = a; sbuf[i] = s;
    }
    __syncthreads();
    // segment max
    float lm = -3.4e38f;
    for (int i = tid; i < deg; i += 128) lm = fmaxf(lm, sc[i]);
#pragma unroll
    for (int off = 32; off >= 1; off >>= 1) lm = fmaxf(lm, __shfl_xor(lm, off));
    if (lane == 0) red[wid] = lm;
    __syncthreads();
    float m = fmaxf(red[0], red[1]);
    __syncthreads();
    // segment sum of exp (stash exp back into sc)
    float ls = 0.f;
    for (int i = tid; i < deg; i += 128) {
      float ex = __expf(sc[i] - m);
      sc[i] = ex;
      ls += ex;
    }
#pragma unroll
    for (int off = 32; off >= 1; off >>= 1) ls += __shfl_xor(ls, off);
    if (lane == 0) red[wid] = ls;
    __syncthreads();
    float inv = 1.f / (red[0] + red[1] + 1e-16f);
    // fold alpha into the att row (each thread owns its own i's — no race)
    for (int i = tid; i < deg; i += 128) {
      float p = sc[i] * inv;
      float4 a = a4[i];
      a.x *= p; a.y *= p; a.z *= p; a.w *= p;
      a4[i] = a;
    }
    __syncthreads();
    // aggregate x[src] with per-basis coefficients (threads = feature dim)
    if (tid < D) {
      float acc0 = 0.f, acc1 = 0.f, acc2 = 0.f, acc3 = 0.f;
      int i = 0;
      for (; i + 1 < deg; i += 2) {  // 2 gathers in flight
        float4 aA = a4[i];     int sA = sbuf[i];
        float4 aB = a4[i + 1]; int sB = sbuf[i + 1];
        float xA = feat[(size_t)sA * D + tid];
        float xB = feat[(size_t)sB * D + tid];
        acc0 += aA.x * xA + aB.x * xB;
        acc1 += aA.y * xA + aB.y * xB;
        acc2 += aA.z * xA + aB.z * xB;
        acc3 += aA.w * xA + aB.w * xB;
      }
      if (i < deg) {
        float4 a = a4[i]; int s = sbuf[i];
        float xv = feat[(size_t)s * D + tid];
        acc0 += a.x * xv; acc1 += a.y * xv; acc2 += a.z * xv; acc3 += a.w * xv;
      }
      float* ag = agg + (size_t)n * (B * D) + tid;
      ag[0 * D] = acc0; ag[1 * D] = acc1; ag[2 * D] = acc2; ag[3 * D] = acc3;
    }
  } else {
    // fallback: recompute path (correct for any deg)
    float lm = -3.4e38f;
    for (int i = tid; i < deg; i += 128) {
      float4 a;
      lm = fmaxf(lm, edge_score_p(ssorted[o0 + i], esorted[o0 + i], att, xq4, xk, &a));
    }
#pragma unroll
    for (int off = 32; off >= 1; off >>= 1) lm = fmaxf(lm, __shfl_xor(lm, off));
    if (lane == 0) red[wid] = lm;
    __syncthreads();
    float m = fmaxf(red[0], red[1]);
    __syncthreads();
    float ls = 0.f;
    for (int i = tid; i < deg; i += 128) {
      float4 a;
      ls += __expf(edge_score_p(ssorted[o0 + i], esorted[o0 + i], att, xq4, xk, &a) - m);
    }
#pragma unroll
    for (int off = 32; off >= 1; off >>= 1) ls += __shfl_xor(ls, off);
    if (lane == 0) red[wid] = ls;
    __syncthreads();
    float inv = 1.f / (red[0] + red[1] + 1e-16f);
    if (tid < D) {
      float acc0 = 0.f, acc1 = 0.f, acc2 = 0.f, acc3 = 0.f;
      for (int i = 0; i < deg; ++i) {
        int s = ssorted[o0 + i];
        float4 a;
        float v = edge_score_p(s, esorted[o0 + i], att, xq4, xk, &a);
        float p = __expf(v - m) * inv;
        float xv = feat[(size_t)s * D + tid];
        acc0 += p * a.x * xv;
        acc1 += p * a.y * xv;
        acc2 += p * a.z * xv;
        acc3 += p * a.w * xv;
      }
      float* ag = agg + (size_t)n * (B * D) + tid;
      ag[0 * D] = acc0; ag[1 * D] = acc1; ag[2 * D] = acc2; ag[3 * D] = acc3;
    }
  }
}

// out[n,o] = sum_k A[n,k] * W[k,o] + bias[o]   (W = basis viewed [400,100]), opt ReLU
// LDS-issue-aware layout: lane = n (64 rows/block). A staged TRANSPOSED [k][n+pad]
// so the per-k A-read is ONE full-width ds_read_b32 (64 consecutive words, free).
// W reads are wave-uniform-address ds_read_b128 (broadcast = free); each feeds
// 4 FMAs from registers. o-split {28,24,24,24} over the 4 waves = exactly 100.
// Per wave per k: ~1 b32 + 6-7 broadcast b128 vs 24-28 FMA -> VALU-bound.
template <bool RELU>
__global__ __launch_bounds__(256) void k_gemm(const float* __restrict__ A,
                                              const float* __restrict__ W,
                                              const float* __restrict__ bias,
                                              float* __restrict__ out) {
  __shared__ float At[64][80];    // [k_local][n], pad 80: fixed-k row read = free
  __shared__ float Wf[64 * 100];  // [k_local][o] flat; reads are uniform-address
  int tid = threadIdx.x;
  int lane = tid & 63;
  int wv = tid >> 6;
  int nblk = blockIdx.x * 64;
  int gn = nblk + lane;
  int o_base = (wv == 0) ? 0 : 28 + (wv - 1) * 24;  // {0,28,52,76}
  float acc[28] = {};

  int a_n = lane;      // staging role: this thread loads A[nblk+a_n][kc+a_kq*16 ..]
  int a_kq = wv;       // 4 waves cover 4 k-quads of 16
  const float* arow = A + (size_t)(nblk + a_n) * 400;
  bool arow_ok = (nblk + a_n) < N;

  for (int kc = 0; kc < 400; kc += 64) {
    __syncthreads();  // previous compute done; safe to overwrite LDS
    // stage A^T: each thread 16 k-values = 4 float4 (coalesced global rows,
    // LDS writes are 64-consecutive-word instructions: conflict-free)
#pragma unroll
    for (int j4 = 0; j4 < 4; ++j4) {
      int k = kc + a_kq * 16 + j4 * 4;
      float4 v = (arow_ok && k + 3 < 400) ? *(const float4*)(arow + k)
                                          : make_float4(0.f, 0.f, 0.f, 0.f);
      int kl = a_kq * 16 + j4 * 4;
      At[kl + 0][a_n] = v.x;
      At[kl + 1][a_n] = v.y;
      At[kl + 2][a_n] = v.z;
      At[kl + 3][a_n] = v.w;
    }
    // stage W rows kc..kc+63: 1600 float4, contiguous (rows of 100 are 4-divisible)
    for (int q = tid; q < 1600; q += 256) {
      int w = q * 4;
      int kl = w / 100;
      int o = w - kl * 100;
      int kg = kc + kl;
      float4 v = (kg < 400) ? *(const float4*)(W + (size_t)kg * 100 + o)
                            : make_float4(0.f, 0.f, 0.f, 0.f);
      *(float4*)&Wf[w] = v;
    }
    __syncthreads();
    // compute: per k, one full-width A read + 6/7 broadcast W reads
#pragma unroll 2
    for (int k = 0; k < 64; ++k) {
      float a = At[k][lane];
      const float* wrow = &Wf[k * 100 + o_base];
#pragma unroll
      for (int q = 0; q < 6; ++q) {
        float4 w4 = *(const float4*)(wrow + 4 * q);
        acc[4 * q + 0] += a * w4.x;
        acc[4 * q + 1] += a * w4.y;
        acc[4 * q + 2] += a * w4.z;
        acc[4 * q + 3] += a * w4.w;
      }
      if (wv == 0) {  // wave-uniform branch: wave 0 owns 7 quads (o 0..27)
        float4 w4 = *(const float4*)(wrow + 24);
        acc[24] += a * w4.x;
        acc[25] += a * w4.y;
        acc[26] += a * w4.z;
        acc[27] += a * w4.w;
      }
    }
  }
  // epilogue
  if (gn < N) {
    int nq = (wv == 0) ? 7 : 6;
    float* orow = out + (size_t)gn * 100 + o_base;
    const float* brow = bias + o_base;
#pragma unroll
    for (int q = 0; q < 7; ++q) {
      if (q < nq) {
        float4 r;
        r.x = acc[4 * q + 0] + brow[4 * q + 0];
        r.y = acc[4 * q + 1] + brow[4 * q + 1];
        r.z = acc[4 * q + 2] + brow[4 * q + 2];
        r.w = acc[4 * q + 3] + brow[4 * q + 3];
        if (RELU) {
          r.x = fmaxf(r.x, 0.f);
          r.y = fmaxf(r.y, 0.f);
          r.z = fmaxf(r.z, 0.f);
          r.w = fmaxf(r.w, 0.f);
        }
        *(float4*)(orow + 4 * q) = r;
      }
    }
  }
}

// ---------------- launch ----------------

extern "C" void kernel_launch(void* const* d_in, const int* in_sizes, int n_in,
                              void* d_out, int out_size, void* d_ws, size_t ws_size,
                              hipStream_t stream) {
  const int* entity = (const int*)d_in[0];
  const int* edge_index = (const int*)d_in[1];
  const int* etype = (const int*)d_in[2];
  // d_in[3] = edge_norm: unused by the reference
  const float* emb = (const float*)d_in[4];
  const float* basis1 = (const float*)d_in[5];
  const float* att1 = (const float*)d_in[6];
  const float* q1 = (const float*)d_in[7];
  const float* k1 = (const float*)d_in[8];
  const float* bias1 = (const float*)d_in[9];
  const float* basis2 = (const float*)d_in[10];
  const float* att2 = (const float*)d_in[11];
  const float* q2 = (const float*)d_in[12];
  const float* k2 = (const float*)d_in[13];
  const float* bias2 = (const float*)d_in[14];
  float* out = (float*)d_out;

  const int* srcArr = edge_index;       // edge_index[0,:]
  const int* dstArr = edge_index + E;   // edge_index[1,:]

  // workspace layout (~106 MB)
  float* ws = (float*)d_ws;
  float* agg = ws;                               // N*B*D = 20,000,000 floats
  float* X1 = agg + (size_t)N * B * D;           // N*D = 5,000,000
  float* xq = X1 + (size_t)N * D;                // N*B
  float* xk = xq + (size_t)N * B;                // N*B
  float* qb = xk + (size_t)N * B;                // B*D
  float* kb = qb + B * D;                        // B*D
  int* ssorted = (int*)(kb + B * D);             // E
  int* esorted = ssorted + E;                    // E
  int* offs = esorted + E;                       // N+1
  int* deg = offs + (N + 1);                     // N
  int* cursor = deg + N;                         // N
  int* incl = cursor + N;                        // N
  int* bsums = incl + N;                         // NB_SCAN

  hipMemsetAsync(deg, 0, N * sizeof(int), stream);
  hipMemsetAsync(cursor, 0, N * sizeof(int), stream);
  k_hist<<<512, 256, 0, stream>>>(dstArr, deg);
  k_scan1<<<NB_SCAN, 256, 0, stream>>>(deg, incl, bsums);
  k_scan2<<<1, 64, 0, stream>>>(bsums, NB_SCAN);
  k_scan3<<<256, 256, 0, stream>>>(incl, bsums, offs);
  k_scatter<<<512, 256, 0, stream>>>(srcArr, dstArr, etype, offs, cursor, ssorted, esorted);
  k_gather<<<1024, 256, 0, stream>>>(emb, entity, X1);

  // ---- layer 1: x = X1, ReLU; x1 stored in d_out ----
  k_qbkb<<<2, 256, 0, stream>>>(basis1, q1, k1, qb, kb);
  k_xqxk<<<(N + 255) / 256, 256, 0, stream>>>(X1, qb, kb, xq, xk);
  k_node<<<N, 128, 0, stream>>>(X1, ssorted, esorted, att1, xq, xk, offs, agg);
  k_gemm<true><<<(N + 63) / 64, 256, 0, stream>>>(agg, basis1, bias1, out);

  // ---- layer 2: x = x1 (in d_out), no ReLU ----
  k_qbkb<<<2, 256, 0, stream>>>(basis2, q2, k2, qb, kb);
  k_xqxk<<<(N + 255) / 256, 256, 0, stream>>>(out, qb, kb, xq, xk);
  k_node<<<N, 128, 0, stream>>>(out, ssorted, esorted, att2, xq, xk, offs, agg);
  k_gemm<false><<<(N + 63) / 64, 256, 0, stream>>>(agg, basis2, bias2, out);
}

// Round 10
// 492.971 us; speedup vs baseline: 1.3058x; 1.3058x over previous
//
#include <hip/hip_runtime.h>

constexpr int N = 50000;
constexpr int E = 400000;
constexpr int D = 100;
constexpr int B = 4;
constexpr float NEG_SLOPE = 0.2f;

constexpr int SCAN_CHUNK = 2048;
constexpr int NB_SCAN = (N + SCAN_CHUNK - 1) / SCAN_CHUNK;  // 25
constexpr int CAP = 128;  // per-node LDS edge cache; deg>CAP falls back (Poisson(8): never)

// ---------------- CSR build (counting sort of edges by dst) ----------------

__global__ void k_hist(const int* __restrict__ dst, int* __restrict__ deg) {
  int i = blockIdx.x * blockDim.x + threadIdx.x;
  int stride = gridDim.x * blockDim.x;
  for (; i < E; i += stride) atomicAdd(&deg[dst[i]], 1);
}

__global__ void k_scan1(const int* __restrict__ deg, int* __restrict__ incl,
                        int* __restrict__ bsums) {
  __shared__ int lds[256];
  int tid = threadIdx.x;
  int base = blockIdx.x * SCAN_CHUNK + tid * 8;
  int v[8]; int s = 0;
#pragma unroll
  for (int j = 0; j < 8; ++j) {
    int idx = base + j;
    int x = (idx < N) ? deg[idx] : 0;
    v[j] = x; s += x;
  }
  lds[tid] = s; __syncthreads();
  for (int off = 1; off < 256; off <<= 1) {
    int t = (tid >= off) ? lds[tid - off] : 0;
    __syncthreads();
    lds[tid] += t;
    __syncthreads();
  }
  int run = lds[tid] - s;  // exclusive prefix within block
#pragma unroll
  for (int j = 0; j < 8; ++j) {
    int idx = base + j;
    run += v[j];
    if (idx < N) incl[idx] = run;  // inclusive scan within block
  }
  if (tid == 255) bsums[blockIdx.x] = lds[255];
}

__global__ void k_scan2(int* __restrict__ bsums, int nb) {
  if (threadIdx.x == 0 && blockIdx.x == 0) {
    int run = 0;
    for (int i = 0; i < nb; ++i) { int t = bsums[i]; bsums[i] = run; run += t; }
  }
}

__global__ void k_scan3(const int* __restrict__ incl, const int* __restrict__ bsums,
                        int* __restrict__ offs) {
  int i = blockIdx.x * blockDim.x + threadIdx.x;
  int stride = gridDim.x * blockDim.x;
  for (; i < N; i += stride) {
    offs[i + 1] = incl[i] + bsums[i / SCAN_CHUNK];
    if (i == 0) offs[0] = 0;
  }
}

// scatter edges into CSR order; permute src/etype into position order so
// downstream kernels read contiguous ranges (no indirect per-edge gathers).
__global__ void k_scatter(const int* __restrict__ srcArr, const int* __restrict__ dst,
                          const int* __restrict__ etype, const int* __restrict__ offs,
                          int* __restrict__ cursor, int* __restrict__ ssorted,
                          int* __restrict__ esorted) {
  int i = blockIdx.x * blockDim.x + threadIdx.x;
  int stride = gridDim.x * blockDim.x;
  for (; i < E; i += stride) {
    int d = dst[i];
    int pos = offs[d] + atomicAdd(&cursor[d], 1);
    ssorted[pos] = srcArr[i];
    esorted[pos] = etype[i];
  }
}

// X1[n,:] = emb[entity[n],:]  — hoist the remap so edge gathers are 1-hop.
__global__ void k_gather(const float* __restrict__ emb, const int* __restrict__ entity,
                         float* __restrict__ X) {
  int idx = blockIdx.x * blockDim.x + threadIdx.x;  // float4 index
  int total = N * (D / 4);
  int stride = gridDim.x * blockDim.x;
  for (; idx < total; idx += stride) {
    int n = idx / (D / 4), c = idx % (D / 4);
    int r = entity[n];
    *(float4*)(X + (size_t)n * D + c * 4) = *(const float4*)(emb + (size_t)r * D + c * 4);
  }
}

// ---------------- per-layer kernels ----------------

// qb[b,i] = sum_o basis[b,i,o] * q[o];  kb likewise.
__global__ void k_qbkb(const float* __restrict__ basis, const float* __restrict__ qv,
                       const float* __restrict__ kv, float* __restrict__ qb,
                       float* __restrict__ kb) {
  int t = blockIdx.x * blockDim.x + threadIdx.x;
  if (t < B * D) {
    const float* row = basis + t * D;  // t = b*D+i -> row (b,i,:)
    float sq = 0.f, sk = 0.f;
    for (int o = 0; o < D; ++o) { float r = row[o]; sq += r * qv[o]; sk += r * kv[o]; }
    qb[t] = sq; kb[t] = sk;
  }
}

// xq[n,b] = x[n,:].qb[b,:] ; xk[n,b] = x[n,:].kb[b,:]   — thread per node.
__global__ __launch_bounds__(256) void k_xqxk(
    const float* __restrict__ X, const float* __restrict__ qb,
    const float* __restrict__ kb, float* __restrict__ xq, float* __restrict__ xk) {
  __shared__ float qb_s[B * D], kb_s[B * D];
  int tid = threadIdx.x;
  for (int i = tid; i < B * D; i += 256) { qb_s[i] = qb[i]; kb_s[i] = kb[i]; }
  __syncthreads();
  int n = blockIdx.x * 256 + tid;
  if (n >= N) return;
  const float* x = X + (size_t)n * D;
  float aq[B] = {}, ak[B] = {};
  for (int i = 0; i < D; i += 4) {
    float4 xv = *(const float4*)(x + i);
#pragma unroll
    for (int b = 0; b < B; ++b) {
      float4 qv = *(const float4*)&qb_s[b * D + i];
      float4 kv = *(const float4*)&kb_s[b * D + i];
      aq[b] += xv.x * qv.x + xv.y * qv.y + xv.z * qv.z + xv.w * qv.w;
      ak[b] += xv.x * kv.x + xv.y * kv.y + xv.z * kv.z + xv.w * kv.w;
    }
  }
  *(float4*)(xq + (size_t)n * 4) = make_float4(aq[0], aq[1], aq[2], aq[3]);
  *(float4*)(xk + (size_t)n * 4) = make_float4(ak[0], ak[1], ak[2], ak[3]);
}

__device__ __forceinline__ float edge_score_p(int s, int et,
                                              const float* __restrict__ att,
                                              const float4 xq4,
                                              const float* __restrict__ xk,
                                              float4* a_out) {
  float4 a = *(const float4*)(att + et * 4);
  float4 xs = *(const float4*)(xk + s * 4);
  float qe = a.x * xq4.x + a.y * xq4.y + a.z * xq4.z + a.w * xq4.w;
  float ke = a.x * xs.x + a.y * xs.y + a.z * xs.z + a.w * xs.w;
  float sc = qe + ke;
  *a_out = a;
  return sc >= 0.f ? sc : NEG_SLOPE * sc;
}

// One block (128 thr) per dst node: softmax over its edges + input-space aggregation.
// agg[n,b,:] = sum_edges alpha_e * att[et,b] * x[src,:]
__global__ __launch_bounds__(128) void k_node(
    const float* __restrict__ feat, const int* __restrict__ ssorted,
    const int* __restrict__ esorted, const float* __restrict__ att,
    const float* __restrict__ xq, const float* __restrict__ xk,
    const int* __restrict__ offs, float* __restrict__ agg) {
  int n = blockIdx.x;
  int tid = threadIdx.x;
  int lane = tid & 63, wid = tid >> 6;
  int o0 = offs[n], o1 = offs[n + 1];
  int deg = o1 - o0;
  float4 xq4 = *(const float4*)(xq + (size_t)n * 4);
  __shared__ float red[2];
  __shared__ float sc[CAP];
  __shared__ float4 a4[CAP];
  __shared__ int sbuf[CAP];

  if (deg <= CAP) {
    // compute each edge score ONCE; cache score, att-row, src in LDS
    for (int i = tid; i < deg; i += 128) {
      int s = ssorted[o0 + i];
      int et = esorted[o0 + i];
      float4 a;
      float v = edge_score_p(s, et, att, xq4, xk, &a);
      sc[i] = v; a4[i] = a; sbuf[i] = s;
    }
    __syncthreads();
    // segment max
    float lm = -3.4e38f;
    for (int i = tid; i < deg; i += 128) lm = fmaxf(lm, sc[i]);
#pragma unroll
    for (int off = 32; off >= 1; off >>= 1) lm = fmaxf(lm, __shfl_xor(lm, off));
    if (lane == 0) red[wid] = lm;
    __syncthreads();
    float m = fmaxf(red[0], red[1]);
    __syncthreads();
    // segment sum of exp (stash exp back into sc)
    float ls = 0.f;
    for (int i = tid; i < deg; i += 128) {
      float ex = __expf(sc[i] - m);
      sc[i] = ex;
      ls += ex;
    }
#pragma unroll
    for (int off = 32; off >= 1; off >>= 1) ls += __shfl_xor(ls, off);
    if (lane == 0) red[wid] = ls;
    __syncthreads();
    float inv = 1.f / (red[0] + red[1] + 1e-16f);
    // fold alpha into the att row (each thread owns its own i's — no race)
    for (int i = tid; i < deg; i += 128) {
      float p = sc[i] * inv;
      float4 a = a4[i];
      a.x *= p; a.y *= p; a.z *= p; a.w *= p;
      a4[i] = a;
    }
    __syncthreads();
    // aggregate x[src] with per-basis coefficients (threads = feature dim)
    if (tid < D) {
      float acc0 = 0.f, acc1 = 0.f, acc2 = 0.f, acc3 = 0.f;
      int i = 0;
      for (; i + 1 < deg; i += 2) {  // 2 gathers in flight
        float4 aA = a4[i];     int sA = sbuf[i];
        float4 aB = a4[i + 1]; int sB = sbuf[i + 1];
        float xA = feat[(size_t)sA * D + tid];
        float xB = feat[(size_t)sB * D + tid];
        acc0 += aA.x * xA + aB.x * xB;
        acc1 += aA.y * xA + aB.y * xB;
        acc2 += aA.z * xA + aB.z * xB;
        acc3 += aA.w * xA + aB.w * xB;
      }
      if (i < deg) {
        float4 a = a4[i]; int s = sbuf[i];
        float xv = feat[(size_t)s * D + tid];
        acc0 += a.x * xv; acc1 += a.y * xv; acc2 += a.z * xv; acc3 += a.w * xv;
      }
      float* ag = agg + (size_t)n * (B * D) + tid;
      ag[0 * D] = acc0; ag[1 * D] = acc1; ag[2 * D] = acc2; ag[3 * D] = acc3;
    }
  } else {
    // fallback: recompute path (correct for any deg)
    float lm = -3.4e38f;
    for (int i = tid; i < deg; i += 128) {
      float4 a;
      lm = fmaxf(lm, edge_score_p(ssorted[o0 + i], esorted[o0 + i], att, xq4, xk, &a));
    }
#pragma unroll
    for (int off = 32; off >= 1; off >>= 1) lm = fmaxf(lm, __shfl_xor(lm, off));
    if (lane == 0) red[wid] = lm;
    __syncthreads();
    float m = fmaxf(red[0], red[1]);
    __syncthreads();
    float ls = 0.f;
    for (int i = tid; i < deg; i += 128) {
      float4 a;
      ls += __expf(edge_score_p(ssorted[o0 + i], esorted[o0 + i], att, xq4, xk, &a) - m);
    }
#pragma unroll
    for (int off = 32; off >= 1; off >>= 1) ls += __shfl_xor(ls, off);
    if (lane == 0) red[wid] = ls;
    __syncthreads();
    float inv = 1.f / (red[0] + red[1] + 1e-16f);
    if (tid < D) {
      float acc0 = 0.f, acc1 = 0.f, acc2 = 0.f, acc3 = 0.f;
      for (int i = 0; i < deg; ++i) {
        int s = ssorted[o0 + i];
        float4 a;
        float v = edge_score_p(s, esorted[o0 + i], att, xq4, xk, &a);
        float p = __expf(v - m) * inv;
        float xv = feat[(size_t)s * D + tid];
        acc0 += p * a.x * xv;
        acc1 += p * a.y * xv;
        acc2 += p * a.z * xv;
        acc3 += p * a.w * xv;
      }
      float* ag = agg + (size_t)n * (B * D) + tid;
      ag[0 * D] = acc0; ag[1 * D] = acc1; ag[2 * D] = acc2; ag[3 * D] = acc3;
    }
  }
}

// out[n,o] = sum_k A[n,k] * W[k,o] + bias[o]   (W = basis viewed [400,100]), opt ReLU
// LDS-INSTRUCTION-MINIMAL design (the currency is LDS issues per FMA, r9 lesson):
// 256 thr = 16 n-groups x 16 o-groups, each thread 8n x 8o = 64 FMA/k fed by
// exactly 4 ds_read_b128 (A:2, W:2). A staged TRANSPOSED At[k][n] with XOR
// block-swizzle (n8 ^= (k>>2)&3): compute reads conflict-free 32B-aligned b128,
// staging scatter degrades only to 4-way (~10% of chunk LDS time). W keeps the
// r5-proven {o_lo, o_lo+64} split (2-way = free). BN=128, BK=64, LDS 64 KB.
template <bool RELU>
__global__ __launch_bounds__(256) void k_gemm(const float* __restrict__ A,
                                              const float* __restrict__ W,
                                              const float* __restrict__ bias,
                                              float* __restrict__ out) {
  __shared__ float At[64 * 128];  // [k][n-swizzled]
  __shared__ float Wf[64 * 128];  // [k][o], o >= 100 zero-padded
  int tid = threadIdx.x;
  int o_g = tid & 15;
  int n_g = tid >> 4;
  int o_lo = o_g * 4;
  int nblk = blockIdx.x * 128;
  float acc[8][8] = {};

  for (int kc = 0; kc < 400; kc += 64) {
    __syncthreads();  // previous compute done; safe to overwrite LDS
    // stage A^T with swizzle: 128 rows x 16 quads = 2048 float4, 8/thread.
    // global: 16 lanes read 256B contiguous per row (coalesced).
#pragma unroll
    for (int j = 0; j < 8; ++j) {
      int idx = tid + j * 256;
      int n_l = idx >> 4;        // 0..127
      int k4 = (idx & 15) * 4;   // 0..60
      int gn2 = nblk + n_l;
      float4 v = (gn2 < N && kc + k4 + 3 < 400)
                     ? *(const float4*)(A + (size_t)gn2 * 400 + kc + k4)
                     : make_float4(0.f, 0.f, 0.f, 0.f);
      int n8 = n_l >> 3, nlo = n_l & 7;
#pragma unroll
      for (int i = 0; i < 4; ++i) {
        int k = k4 + i;
        At[k * 128 + ((n8 ^ ((k >> 2) & 3)) << 3) + nlo] = (&v.x)[i];
      }
    }
    // stage W: 64 rows x 32 quads = 2048 float4, contiguous writes (o>=100 -> 0)
#pragma unroll
    for (int j = 0; j < 8; ++j) {
      int idx = tid + j * 256;
      int kl = idx >> 5;         // 0..63
      int o4 = (idx & 31) * 4;   // 0..124
      int kg = kc + kl;
      float4 v = (o4 < D && kg < 400)
                     ? *(const float4*)(W + (size_t)kg * D + o4)
                     : make_float4(0.f, 0.f, 0.f, 0.f);
      *(float4*)&Wf[kl * 128 + o4] = v;
    }
    __syncthreads();
    // compute: per k exactly 4 b128 reads feed 64 FMAs
#pragma unroll 4
    for (int k = 0; k < 64; ++k) {
      int abase = k * 128 + ((n_g ^ ((k >> 2) & 3)) << 3);
      float4 a0 = *(const float4*)&At[abase];
      float4 a1 = *(const float4*)&At[abase + 4];
      float4 w0 = *(const float4*)&Wf[k * 128 + o_lo];
      float4 w1 = *(const float4*)&Wf[k * 128 + o_lo + 64];
      float av[8] = {a0.x, a0.y, a0.z, a0.w, a1.x, a1.y, a1.z, a1.w};
      float wv[8] = {w0.x, w0.y, w0.z, w0.w, w1.x, w1.y, w1.z, w1.w};
#pragma unroll
      for (int i = 0; i < 8; ++i)
#pragma unroll
        for (int jj = 0; jj < 8; ++jj) acc[i][jj] += av[i] * wv[jj];
    }
  }
  // epilogue: cols {o_lo..o_lo+3} always valid (<=63); {o_lo+64..+67} if <100
  bool hi_ok = (o_lo + 64 + 3) < D;  // o_g <= 8
  float4 b0 = *(const float4*)(bias + o_lo);
  float4 b1 = hi_ok ? *(const float4*)(bias + o_lo + 64) : make_float4(0, 0, 0, 0);
#pragma unroll
  for (int i = 0; i < 8; ++i) {
    int gn = nblk + n_g * 8 + i;
    if (gn < N) {
      float4 r0, r1;
      r0.x = acc[i][0] + b0.x; r0.y = acc[i][1] + b0.y;
      r0.z = acc[i][2] + b0.z; r0.w = acc[i][3] + b0.w;
      r1.x = acc[i][4] + b1.x; r1.y = acc[i][5] + b1.y;
      r1.z = acc[i][6] + b1.z; r1.w = acc[i][7] + b1.w;
      if (RELU) {
        r0.x = fmaxf(r0.x, 0.f); r0.y = fmaxf(r0.y, 0.f);
        r0.z = fmaxf(r0.z, 0.f); r0.w = fmaxf(r0.w, 0.f);
        r1.x = fmaxf(r1.x, 0.f); r1.y = fmaxf(r1.y, 0.f);
        r1.z = fmaxf(r1.z, 0.f); r1.w = fmaxf(r1.w, 0.f);
      }
      *(float4*)(out + (size_t)gn * D + o_lo) = r0;
      if (hi_ok) *(float4*)(out + (size_t)gn * D + o_lo + 64) = r1;
    }
  }
}

// ---------------- launch ----------------

extern "C" void kernel_launch(void* const* d_in, const int* in_sizes, int n_in,
                              void* d_out, int out_size, void* d_ws, size_t ws_size,
                              hipStream_t stream) {
  const int* entity = (const int*)d_in[0];
  const int* edge_index = (const int*)d_in[1];
  const int* etype = (const int*)d_in[2];
  // d_in[3] = edge_norm: unused by the reference
  const float* emb = (const float*)d_in[4];
  const float* basis1 = (const float*)d_in[5];
  const float* att1 = (const float*)d_in[6];
  const float* q1 = (const float*)d_in[7];
  const float* k1 = (const float*)d_in[8];
  const float* bias1 = (const float*)d_in[9];
  const float* basis2 = (const float*)d_in[10];
  const float* att2 = (const float*)d_in[11];
  const float* q2 = (const float*)d_in[12];
  const float* k2 = (const float*)d_in[13];
  const float* bias2 = (const float*)d_in[14];
  float* out = (float*)d_out;

  const int* srcArr = edge_index;       // edge_index[0,:]
  const int* dstArr = edge_index + E;   // edge_index[1,:]

  // workspace layout (~106 MB)
  float* ws = (float*)d_ws;
  float* agg = ws;                               // N*B*D = 20,000,000 floats
  float* X1 = agg + (size_t)N * B * D;           // N*D = 5,000,000
  float* xq = X1 + (size_t)N * D;                // N*B
  float* xk = xq + (size_t)N * B;                // N*B
  float* qb = xk + (size_t)N * B;                // B*D
  float* kb = qb + B * D;                        // B*D
  int* ssorted = (int*)(kb + B * D);             // E
  int* esorted = ssorted + E;                    // E
  int* offs = esorted + E;                       // N+1
  int* deg = offs + (N + 1);                     // N
  int* cursor = deg + N;                         // N
  int* incl = cursor + N;                        // N
  int* bsums = incl + N;                         // NB_SCAN

  hipMemsetAsync(deg, 0, N * sizeof(int), stream);
  hipMemsetAsync(cursor, 0, N * sizeof(int), stream);
  k_hist<<<512, 256, 0, stream>>>(dstArr, deg);
  k_scan1<<<NB_SCAN, 256, 0, stream>>>(deg, incl, bsums);
  k_scan2<<<1, 64, 0, stream>>>(bsums, NB_SCAN);
  k_scan3<<<256, 256, 0, stream>>>(incl, bsums, offs);
  k_scatter<<<512, 256, 0, stream>>>(srcArr, dstArr, etype, offs, cursor, ssorted, esorted);
  k_gather<<<1024, 256, 0, stream>>>(emb, entity, X1);

  // ---- layer 1: x = X1, ReLU; x1 stored in d_out ----
  k_qbkb<<<2, 256, 0, stream>>>(basis1, q1, k1, qb, kb);
  k_xqxk<<<(N + 255) / 256, 256, 0, stream>>>(X1, qb, kb, xq, xk);
  k_node<<<N, 128, 0, stream>>>(X1, ssorted, esorted, att1, xq, xk, offs, agg);
  k_gemm<true><<<(N + 127) / 128, 256, 0, stream>>>(agg, basis1, bias1, out);

  // ---- layer 2: x = x1 (in d_out), no ReLU ----
  k_qbkb<<<2, 256, 0, stream>>>(basis2, q2, k2, qb, kb);
  k_xqxk<<<(N + 255) / 256, 256, 0, stream>>>(out, qb, kb, xq, xk);
  k_node<<<N, 128, 0, stream>>>(out, ssorted, esorted, att2, xq, xk, offs, agg);
  k_gemm<false><<<(N + 127) / 128, 256, 0, stream>>>(agg, basis2, bias2, out);
}

// Round 11
// 444.738 us; speedup vs baseline: 1.4474x; 1.1085x over previous
//
#include <hip/hip_runtime.h>

constexpr int N = 50000;
constexpr int NPAD = 50048;  // 782*64, MFMA row padding
constexpr int E = 400000;
constexpr int D = 100;
constexpr int B = 4;
constexpr float NEG_SLOPE = 0.2f;

constexpr int SCAN_CHUNK = 2048;
constexpr int NB_SCAN = (N + SCAN_CHUNK - 1) / SCAN_CHUNK;  // 25
constexpr int CAP = 128;  // per-node LDS edge cache; deg>CAP falls back (Poisson(8): never)

typedef __attribute__((ext_vector_type(8))) short short8v;
typedef __attribute__((ext_vector_type(4))) float f32x4;

__device__ __forceinline__ unsigned short f2bf(float f) {
  unsigned int u = __float_as_uint(f);
  unsigned int r = u + 0x7FFFu + ((u >> 16) & 1u);  // RNE
  return (unsigned short)(r >> 16);
}
__device__ __forceinline__ float bf2f(unsigned short h) {
  return __uint_as_float((unsigned int)h << 16);
}

// ---------------- CSR build (counting sort of edges by dst) ----------------

__global__ void k_hist(const int* __restrict__ dst, int* __restrict__ deg) {
  int i = blockIdx.x * blockDim.x + threadIdx.x;
  int stride = gridDim.x * blockDim.x;
  for (; i < E; i += stride) atomicAdd(&deg[dst[i]], 1);
}

__global__ void k_scan1(const int* __restrict__ deg, int* __restrict__ incl,
                        int* __restrict__ bsums) {
  __shared__ int lds[256];
  int tid = threadIdx.x;
  int base = blockIdx.x * SCAN_CHUNK + tid * 8;
  int v[8]; int s = 0;
#pragma unroll
  for (int j = 0; j < 8; ++j) {
    int idx = base + j;
    int x = (idx < N) ? deg[idx] : 0;
    v[j] = x; s += x;
  }
  lds[tid] = s; __syncthreads();
  for (int off = 1; off < 256; off <<= 1) {
    int t = (tid >= off) ? lds[tid - off] : 0;
    __syncthreads();
    lds[tid] += t;
    __syncthreads();
  }
  int run = lds[tid] - s;  // exclusive prefix within block
#pragma unroll
  for (int j = 0; j < 8; ++j) {
    int idx = base + j;
    run += v[j];
    if (idx < N) incl[idx] = run;  // inclusive scan within block
  }
  if (tid == 255) bsums[blockIdx.x] = lds[255];
}

__global__ void k_scan2(int* __restrict__ bsums, int nb) {
  if (threadIdx.x == 0 && blockIdx.x == 0) {
    int run = 0;
    for (int i = 0; i < nb; ++i) { int t = bsums[i]; bsums[i] = run; run += t; }
  }
}

__global__ void k_scan3(const int* __restrict__ incl, const int* __restrict__ bsums,
                        int* __restrict__ offs) {
  int i = blockIdx.x * blockDim.x + threadIdx.x;
  int stride = gridDim.x * blockDim.x;
  for (; i < N; i += stride) {
    offs[i + 1] = incl[i] + bsums[i / SCAN_CHUNK];
    if (i == 0) offs[0] = 0;
  }
}

// scatter edges into CSR order; permute src/etype into position order so
// downstream kernels read contiguous ranges (no indirect per-edge gathers).
__global__ void k_scatter(const int* __restrict__ srcArr, const int* __restrict__ dst,
                          const int* __restrict__ etype, const int* __restrict__ offs,
                          int* __restrict__ cursor, int* __restrict__ ssorted,
                          int* __restrict__ esorted) {
  int i = blockIdx.x * blockDim.x + threadIdx.x;
  int stride = gridDim.x * blockDim.x;
  for (; i < E; i += stride) {
    int d = dst[i];
    int pos = offs[d] + atomicAdd(&cursor[d], 1);
    ssorted[pos] = srcArr[i];
    esorted[pos] = etype[i];
  }
}

// X1[n,:] = emb[entity[n],:]  — hoist the remap so edge gathers are 1-hop.
__global__ void k_gather(const float* __restrict__ emb, const int* __restrict__ entity,
                         float* __restrict__ X) {
  int idx = blockIdx.x * blockDim.x + threadIdx.x;  // float4 index
  int total = N * (D / 4);
  int stride = gridDim.x * blockDim.x;
  for (; idx < total; idx += stride) {
    int n = idx / (D / 4), c = idx % (D / 4);
    int r = entity[n];
    *(float4*)(X + (size_t)n * D + c * 4) = *(const float4*)(emb + (size_t)r * D + c * 4);
  }
}

// Wt[o][k] bf16 hi/lo, padded to [112][416] with zeros, for both layers.
__global__ void k_wprep(const float* __restrict__ W1, const float* __restrict__ W2,
                        unsigned short* __restrict__ h1, unsigned short* __restrict__ l1,
                        unsigned short* __restrict__ h2, unsigned short* __restrict__ l2) {
  int idx = blockIdx.x * blockDim.x + threadIdx.x;
  if (idx >= 112 * 416) return;
  int o = idx / 416, k = idx % 416;
  bool ok = (o < D) && (k < 400);
  float v1 = ok ? W1[k * D + o] : 0.f;
  float v2 = ok ? W2[k * D + o] : 0.f;
  unsigned short a = f2bf(v1);
  h1[idx] = a; l1[idx] = f2bf(v1 - bf2f(a));
  unsigned short b = f2bf(v2);
  h2[idx] = b; l2[idx] = f2bf(v2 - bf2f(b));
}

// ---------------- per-layer kernels ----------------

// qb[b,i] = sum_o basis[b,i,o] * q[o];  kb likewise.
__global__ void k_qbkb(const float* __restrict__ basis, const float* __restrict__ qv,
                       const float* __restrict__ kv, float* __restrict__ qb,
                       float* __restrict__ kb) {
  int t = blockIdx.x * blockDim.x + threadIdx.x;
  if (t < B * D) {
    const float* row = basis + t * D;  // t = b*D+i -> row (b,i,:)
    float sq = 0.f, sk = 0.f;
    for (int o = 0; o < D; ++o) { float r = row[o]; sq += r * qv[o]; sk += r * kv[o]; }
    qb[t] = sq; kb[t] = sk;
  }
}

// xq[n,b] = x[n,:].qb[b,:] ; xk[n,b] = x[n,:].kb[b,:]   — thread per node.
__global__ __launch_bounds__(256) void k_xqxk(
    const float* __restrict__ X, const float* __restrict__ qb,
    const float* __restrict__ kb, float* __restrict__ xq, float* __restrict__ xk) {
  __shared__ float qb_s[B * D], kb_s[B * D];
  int tid = threadIdx.x;
  for (int i = tid; i < B * D; i += 256) { qb_s[i] = qb[i]; kb_s[i] = kb[i]; }
  __syncthreads();
  int n = blockIdx.x * 256 + tid;
  if (n >= N) return;
  const float* x = X + (size_t)n * D;
  float aq[B] = {}, ak[B] = {};
  for (int i = 0; i < D; i += 4) {
    float4 xv = *(const float4*)(x + i);
#pragma unroll
    for (int b = 0; b < B; ++b) {
      float4 qv = *(const float4*)&qb_s[b * D + i];
      float4 kv = *(const float4*)&kb_s[b * D + i];
      aq[b] += xv.x * qv.x + xv.y * qv.y + xv.z * qv.z + xv.w * qv.w;
      ak[b] += xv.x * kv.x + xv.y * kv.y + xv.z * kv.z + xv.w * kv.w;
    }
  }
  *(float4*)(xq + (size_t)n * 4) = make_float4(aq[0], aq[1], aq[2], aq[3]);
  *(float4*)(xk + (size_t)n * 4) = make_float4(ak[0], ak[1], ak[2], ak[3]);
}

__device__ __forceinline__ float edge_score_p(int s, int et,
                                              const float* __restrict__ att,
                                              const float4 xq4,
                                              const float* __restrict__ xk,
                                              float4* a_out) {
  float4 a = *(const float4*)(att + et * 4);
  float4 xs = *(const float4*)(xk + s * 4);
  float qe = a.x * xq4.x + a.y * xq4.y + a.z * xq4.z + a.w * xq4.w;
  float ke = a.x * xs.x + a.y * xs.y + a.z * xs.z + a.w * xs.w;
  float sc = qe + ke;
  *a_out = a;
  return sc >= 0.f ? sc : NEG_SLOPE * sc;
}

__device__ __forceinline__ void write_bf_pair(unsigned short* __restrict__ Ahi,
                                              unsigned short* __restrict__ Alo,
                                              size_t idx, float v) {
  unsigned short h = f2bf(v);
  Ahi[idx] = h;
  Alo[idx] = f2bf(v - bf2f(h));
}

// One block (128 thr) per dst node: softmax over its edges + input-space aggregation.
// Output written as SPLIT-BF16 (hi/lo) rows of A for the MFMA GEMM: A[n][b*100+d].
__global__ __launch_bounds__(128) void k_node(
    const float* __restrict__ feat, const int* __restrict__ ssorted,
    const int* __restrict__ esorted, const float* __restrict__ att,
    const float* __restrict__ xq, const float* __restrict__ xk,
    const int* __restrict__ offs, unsigned short* __restrict__ Ahi,
    unsigned short* __restrict__ Alo) {
  int n = blockIdx.x;
  int tid = threadIdx.x;
  int lane = tid & 63, wid = tid >> 6;
  int o0 = offs[n], o1 = offs[n + 1];
  int deg = o1 - o0;
  float4 xq4 = *(const float4*)(xq + (size_t)n * 4);
  __shared__ float red[2];
  __shared__ float sc[CAP];
  __shared__ float4 a4[CAP];
  __shared__ int sbuf[CAP];

  if (deg <= CAP) {
    for (int i = tid; i < deg; i += 128) {
      int s = ssorted[o0 + i];
      int et = esorted[o0 + i];
      float4 a;
      float v = edge_score_p(s, et, att, xq4, xk, &a);
      sc[i] = v; a4[i] = a; sbuf[i] = s;
    }
    __syncthreads();
    float lm = -3.4e38f;
    for (int i = tid; i < deg; i += 128) lm = fmaxf(lm, sc[i]);
#pragma unroll
    for (int off = 32; off >= 1; off >>= 1) lm = fmaxf(lm, __shfl_xor(lm, off));
    if (lane == 0) red[wid] = lm;
    __syncthreads();
    float m = fmaxf(red[0], red[1]);
    __syncthreads();
    float ls = 0.f;
    for (int i = tid; i < deg; i += 128) {
      float ex = __expf(sc[i] - m);
      sc[i] = ex;
      ls += ex;
    }
#pragma unroll
    for (int off = 32; off >= 1; off >>= 1) ls += __shfl_xor(ls, off);
    if (lane == 0) red[wid] = ls;
    __syncthreads();
    float inv = 1.f / (red[0] + red[1] + 1e-16f);
    for (int i = tid; i < deg; i += 128) {
      float p = sc[i] * inv;
      float4 a = a4[i];
      a.x *= p; a.y *= p; a.z *= p; a.w *= p;
      a4[i] = a;
    }
    __syncthreads();
    if (tid < D) {
      float acc0 = 0.f, acc1 = 0.f, acc2 = 0.f, acc3 = 0.f;
      int i = 0;
      for (; i + 1 < deg; i += 2) {
        float4 aA = a4[i];     int sA = sbuf[i];
        float4 aB = a4[i + 1]; int sB = sbuf[i + 1];
        float xA = feat[(size_t)sA * D + tid];
        float xB = feat[(size_t)sB * D + tid];
        acc0 += aA.x * xA + aB.x * xB;
        acc1 += aA.y * xA + aB.y * xB;
        acc2 += aA.z * xA + aB.z * xB;
        acc3 += aA.w * xA + aB.w * xB;
      }
      if (i < deg) {
        float4 a = a4[i]; int s = sbuf[i];
        float xv = feat[(size_t)s * D + tid];
        acc0 += a.x * xv; acc1 += a.y * xv; acc2 += a.z * xv; acc3 += a.w * xv;
      }
      size_t base = (size_t)n * 400 + tid;
      write_bf_pair(Ahi, Alo, base + 0 * D, acc0);
      write_bf_pair(Ahi, Alo, base + 1 * D, acc1);
      write_bf_pair(Ahi, Alo, base + 2 * D, acc2);
      write_bf_pair(Ahi, Alo, base + 3 * D, acc3);
    }
  } else {
    float lm = -3.4e38f;
    for (int i = tid; i < deg; i += 128) {
      float4 a;
      lm = fmaxf(lm, edge_score_p(ssorted[o0 + i], esorted[o0 + i], att, xq4, xk, &a));
    }
#pragma unroll
    for (int off = 32; off >= 1; off >>= 1) lm = fmaxf(lm, __shfl_xor(lm, off));
    if (lane == 0) red[wid] = lm;
    __syncthreads();
    float m = fmaxf(red[0], red[1]);
    __syncthreads();
    float ls = 0.f;
    for (int i = tid; i < deg; i += 128) {
      float4 a;
      ls += __expf(edge_score_p(ssorted[o0 + i], esorted[o0 + i], att, xq4, xk, &a) - m);
    }
#pragma unroll
    for (int off = 32; off >= 1; off >>= 1) ls += __shfl_xor(ls, off);
    if (lane == 0) red[wid] = ls;
    __syncthreads();
    float inv = 1.f / (red[0] + red[1] + 1e-16f);
    if (tid < D) {
      float acc0 = 0.f, acc1 = 0.f, acc2 = 0.f, acc3 = 0.f;
      for (int i = 0; i < deg; ++i) {
        int s = ssorted[o0 + i];
        float4 a;
        float v = edge_score_p(s, esorted[o0 + i], att, xq4, xk, &a);
        float p = __expf(v - m) * inv;
        float xv = feat[(size_t)s * D + tid];
        acc0 += p * a.x * xv;
        acc1 += p * a.y * xv;
        acc2 += p * a.z * xv;
        acc3 += p * a.w * xv;
      }
      size_t base = (size_t)n * 400 + tid;
      write_bf_pair(Ahi, Alo, base + 0 * D, acc0);
      write_bf_pair(Ahi, Alo, base + 1 * D, acc1);
      write_bf_pair(Ahi, Alo, base + 2 * D, acc2);
      write_bf_pair(Ahi, Alo, base + 3 * D, acc3);
    }
  }
}

// out[n,o] = sum_k A[n,k]*W[k,o] + bias[o] via bf16 MFMA, split precision:
// A = ah + al, W = wh + wl (bf16 hi/lo); D += ah*wh + al*wh + ah*wl.
// No LDS, no barriers: wave owns 16 rows; 7 o-tiles of 16 (100 padded to 112);
// 13 K-chunks of 32 (400 padded). A-frag: lane holds row (l&15), k = kgrp*8+j
// (16B coalesced load). B-frag from Wt[o][k]: col (l&15), same k slice. C/D:
// col = l&15, row = kgrp*4 + reg  [HW-verified mapping].
__global__ __launch_bounds__(256) void k_mfma(
    const unsigned short* __restrict__ Ahi, const unsigned short* __restrict__ Alo,
    const unsigned short* __restrict__ Wth, const unsigned short* __restrict__ Wtl,
    const float* __restrict__ bias, float* __restrict__ out, int relu) {
  int tid = threadIdx.x;
  int lane = tid & 63;
  int wv = tid >> 6;
  int nbase = blockIdx.x * 64 + wv * 16;
  int r16 = lane & 15;   // A row / B col / D col selector
  int kgrp = lane >> 4;  // 0..3
  f32x4 acc[7];
#pragma unroll
  for (int t = 0; t < 7; ++t) acc[t] = (f32x4){0.f, 0.f, 0.f, 0.f};

  const unsigned short* arow_hi = Ahi + (size_t)(nbase + r16) * 400;
  const unsigned short* arow_lo = Alo + (size_t)(nbase + r16) * 400;

#pragma unroll 1
  for (int kc = 0; kc < 400; kc += 32) {
    int kofs = kc + kgrp * 8;
    short8v ah, al;
    if (kofs < 400) {  // last chunk: kgrp 2,3 land in pad -> zero
      ah = *(const short8v*)(arow_hi + kofs);
      al = *(const short8v*)(arow_lo + kofs);
    } else {
      ah = (short8v){0, 0, 0, 0, 0, 0, 0, 0};
      al = ah;
    }
#pragma unroll
    for (int t = 0; t < 7; ++t) {
      size_t wb = (size_t)(t * 16 + r16) * 416 + kofs;  // Wt padded: always in-bounds
      short8v bh = *(const short8v*)(Wth + wb);
      short8v bl = *(const short8v*)(Wtl + wb);
      acc[t] = __builtin_amdgcn_mfma_f32_16x16x32_bf16(ah, bh, acc[t], 0, 0, 0);
      acc[t] = __builtin_amdgcn_mfma_f32_16x16x32_bf16(al, bh, acc[t], 0, 0, 0);
      acc[t] = __builtin_amdgcn_mfma_f32_16x16x32_bf16(ah, bl, acc[t], 0, 0, 0);
    }
  }
  // epilogue: D col = r16, D row = kgrp*4 + r
#pragma unroll
  for (int t = 0; t < 7; ++t) {
    int o = t * 16 + r16;
    if (o < D) {
      float bv = bias[o];
#pragma unroll
      for (int r = 0; r < 4; ++r) {
        int gn = nbase + kgrp * 4 + r;
        if (gn < N) {
          float v = acc[t][r] + bv;
          if (relu) v = fmaxf(v, 0.f);
          out[(size_t)gn * D + o] = v;
        }
      }
    }
  }
}

// ---------------- launch ----------------

extern "C" void kernel_launch(void* const* d_in, const int* in_sizes, int n_in,
                              void* d_out, int out_size, void* d_ws, size_t ws_size,
                              hipStream_t stream) {
  const int* entity = (const int*)d_in[0];
  const int* edge_index = (const int*)d_in[1];
  const int* etype = (const int*)d_in[2];
  // d_in[3] = edge_norm: unused by the reference
  const float* emb = (const float*)d_in[4];
  const float* basis1 = (const float*)d_in[5];
  const float* att1 = (const float*)d_in[6];
  const float* q1 = (const float*)d_in[7];
  const float* k1 = (const float*)d_in[8];
  const float* bias1 = (const float*)d_in[9];
  const float* basis2 = (const float*)d_in[10];
  const float* att2 = (const float*)d_in[11];
  const float* q2 = (const float*)d_in[12];
  const float* k2 = (const float*)d_in[13];
  const float* bias2 = (const float*)d_in[14];
  float* out = (float*)d_out;

  const int* srcArr = edge_index;       // edge_index[0,:]
  const int* dstArr = edge_index + E;   // edge_index[1,:]

  // workspace layout (~104.5 MB)
  unsigned short* Ahi = (unsigned short*)d_ws;       // NPAD*400 bf16
  unsigned short* Alo = Ahi + (size_t)NPAD * 400;    // NPAD*400 bf16
  float* X1 = (float*)(Alo + (size_t)NPAD * 400);    // N*D floats
  float* xq = X1 + (size_t)N * D;                    // N*B
  float* xk = xq + (size_t)N * B;                    // N*B
  float* qb = xk + (size_t)N * B;                    // B*D
  float* kb = qb + B * D;                            // B*D
  unsigned short* Wth1 = (unsigned short*)(kb + B * D);  // 112*416 each
  unsigned short* Wtl1 = Wth1 + 112 * 416;
  unsigned short* Wth2 = Wtl1 + 112 * 416;
  unsigned short* Wtl2 = Wth2 + 112 * 416;
  int* ssorted = (int*)(Wtl2 + 112 * 416);           // E
  int* esorted = ssorted + E;                        // E
  int* offs = esorted + E;                           // N+1
  int* deg = offs + (N + 1);                         // N
  int* cursor = deg + N;                             // N
  int* incl = cursor + N;                            // N
  int* bsums = incl + N;                             // NB_SCAN

  hipMemsetAsync(deg, 0, N * sizeof(int), stream);
  hipMemsetAsync(cursor, 0, N * sizeof(int), stream);
  k_hist<<<512, 256, 0, stream>>>(dstArr, deg);
  k_scan1<<<NB_SCAN, 256, 0, stream>>>(deg, incl, bsums);
  k_scan2<<<1, 64, 0, stream>>>(bsums, NB_SCAN);
  k_scan3<<<256, 256, 0, stream>>>(incl, bsums, offs);
  k_scatter<<<512, 256, 0, stream>>>(srcArr, dstArr, etype, offs, cursor, ssorted, esorted);
  k_gather<<<1024, 256, 0, stream>>>(emb, entity, X1);
  k_wprep<<<(112 * 416 + 255) / 256, 256, 0, stream>>>(basis1, basis2, Wth1, Wtl1, Wth2, Wtl2);

  // ---- layer 1: x = X1, ReLU; x1 stored in d_out ----
  k_qbkb<<<2, 256, 0, stream>>>(basis1, q1, k1, qb, kb);
  k_xqxk<<<(N + 255) / 256, 256, 0, stream>>>(X1, qb, kb, xq, xk);
  k_node<<<N, 128, 0, stream>>>(X1, ssorted, esorted, att1, xq, xk, offs, Ahi, Alo);
  k_mfma<<<NPAD / 64, 256, 0, stream>>>(Ahi, Alo, Wth1, Wtl1, bias1, out, 1);

  // ---- layer 2: x = x1 (in d_out), no ReLU ----
  k_qbkb<<<2, 256, 0, stream>>>(basis2, q2, k2, qb, kb);
  k_xqxk<<<(N + 255) / 256, 256, 0, stream>>>(out, qb, kb, xq, xk);
  k_node<<<N, 128, 0, stream>>>(out, ssorted, esorted, att2, xq, xk, offs, Ahi, Alo);
  k_mfma<<<NPAD / 64, 256, 0, stream>>>(Ahi, Alo, Wth2, Wtl2, bias2, out, 0);
}